// Round 6
// baseline (5146.652 us; speedup 1.0000x reference)
//
#include <hip/hip_runtime.h>

#define B_ 64
#define T_ 512
#define D_ 256
#define H_ 1024
#define O_ 256
#define KTOT 1280   // D_ + H_
#define NBLK 256
#define NTHR 256

typedef __bf16 bf16x8 __attribute__((ext_vector_type(8)));
typedef float f32x4 __attribute__((ext_vector_type(4)));

__device__ __forceinline__ unsigned short f2bf(float f) {
    unsigned int u = __builtin_bit_cast(unsigned int, f);
    unsigned int r = (u + 0x7fffu + ((u >> 16) & 1u)) >> 16;
    return (unsigned short)r;
}
__device__ __forceinline__ float sigmoid_f(float x) { return 1.f / (1.f + __expf(-x)); }
__device__ __forceinline__ float tanh_f(float x)    { return 1.f - 2.f / (1.f + __expf(2.f * x)); }

// sync: per-step arrival bytes arr[t][1024], one byte per (blk,wave). 16 lines/t.
#define SYNC_INTS (T_ * 1024 / 4)   // 131072 ints = 512 KB

__global__ void zero_sync(int* s) { s[blockIdx.x * 256 + threadIdx.x] = 0; }

// Pack [W_ih | W_hh] rows into gate-interleaved bf16 rows p = 4*hcol + g
// (orig row = g*1024 + hcol); also combined bias, and W_out -> bf16.
__global__ __launch_bounds__(256) void pack_weights(
    const float* __restrict__ Wih, const float* __restrict__ Whh,
    const float* __restrict__ bih, const float* __restrict__ bhh,
    const float* __restrict__ Wout,
    unsigned short* __restrict__ Wp, float* __restrict__ bpk,
    unsigned short* __restrict__ Wo)
{
    int bid = blockIdx.x, tid = threadIdx.x;
    if (bid < 4096) {
        int g = bid & 3, hc = bid >> 2;
        int row = g * 1024 + hc;
        for (int e = tid; e < KTOT; e += 256) {
            float v = (e < D_) ? Wih[(size_t)row * D_ + e] : Whh[(size_t)row * H_ + (e - D_)];
            Wp[(size_t)bid * KTOT + e] = f2bf(v);
        }
        if (tid == 0) bpk[bid] = bih[row] + bhh[row];
    } else {
        int r = bid - 4096;
        for (int e = tid; e < H_; e += 256)
            Wo[(size_t)r * H_ + e] = f2bf(Wout[(size_t)r * H_ + e]);
    }
}

// x [B,T,D] f32 -> xt [T,B,D] bf16
__global__ __launch_bounds__(256) void x_pack(const float* __restrict__ x,
                                              unsigned short* __restrict__ xt)
{
    int bid = blockIdx.x;            // = b*512 + t
    int b = bid >> 9, t = bid & 511;
    int d = threadIdx.x;
    xt[((size_t)t * B_ + b) * D_ + d] = f2bf(x[(size_t)bid * D_ + d]);
}

__global__ __launch_bounds__(NTHR, 1) void lstm_scan(
    const unsigned short* __restrict__ Wp, const float* __restrict__ bpk,
    const unsigned short* __restrict__ xt, unsigned short* __restrict__ hs,
    int* __restrict__ sync)
{
    const int tid  = threadIdx.x;
    const int w    = tid >> 6, lane = tid & 63;
    const int blk  = blockIdx.x;
    const int n    = lane & 15, kg = lane >> 4;
    const int gq   = n & 3;
    const int m0   = w * 16;

    unsigned char* arrB = (unsigned char*)sync;

    // Per-wave LDS staging for packed h stores: st[w][row 0..15][col 0..3]
    __shared__ unsigned short st[4][16][4];

    // Preload this wave's weight fragments: 40 x bf16x8, reused 512 steps.
    bf16x8 wf[40];
    {
        const bf16x8* wp8 = (const bf16x8*)(Wp + (size_t)(blk * 16 + n) * KTOT + kg * 8);
        #pragma unroll
        for (int kk = 0; kk < 40; ++kk) wf[kk] = wp8[kk * 4];
    }
    // Pin in registers (opaque redefinition: no remat/sinking into the loop).
    #pragma unroll
    for (int kk = 0; kk < 40; ++kk) asm volatile("" : "+v"(wf[kk]));

    const float bias = bpk[blk * 16 + n];

    float cc[4] = {0.f, 0.f, 0.f, 0.f};

    for (int t = 0; t < T_; ++t) {
        f32x4 ac[4];
        f32x4 z = {0.f, 0.f, 0.f, 0.f};
        ac[0] = z; ac[1] = z; ac[2] = z; ac[3] = z;

        // x-part: independent of h_{t-1}; overlaps the arrival wait below.
        {
            const bf16x8* ax = (const bf16x8*)(xt + ((size_t)t * B_ + m0 + n) * D_ + kg * 8);
            #pragma unroll
            for (int kk = 0; kk < 8; ++kk) {
                bf16x8 a = ax[kk * 4];
                ac[kk & 3] = __builtin_amdgcn_mfma_f32_16x16x32_bf16(a, wf[kk], ac[kk & 3], 0, 0, 0);
            }
        }

        if (t > 0) {
            // Direct sweep: this wave checks ALL 1024 arrival bytes of step
            // t-1 (16 lines) with 4 pipelined dword loads per lane. 2-hop
            // sync: producer byte-store -> consumer detect. No aggregator.
            const int* ap = (const int*)(arrB + (size_t)(t - 1) * 1024) + lane * 4;
            for (;;) {
                int v0 = __hip_atomic_load(ap + 0, __ATOMIC_RELAXED, __HIP_MEMORY_SCOPE_AGENT);
                int v1 = __hip_atomic_load(ap + 1, __ATOMIC_RELAXED, __HIP_MEMORY_SCOPE_AGENT);
                int v2 = __hip_atomic_load(ap + 2, __ATOMIC_RELAXED, __HIP_MEMORY_SCOPE_AGENT);
                int v3 = __hip_atomic_load(ap + 3, __ATOMIC_RELAXED, __HIP_MEMORY_SCOPE_AGENT);
                int ok = (v0 == 0x01010101) & (v1 == 0x01010101) &
                         (v2 == 0x01010101) & (v3 == 0x01010101);
                if (__all(ok)) break;
            }

            const bf16x8* ah = (const bf16x8*)(hs + ((size_t)(t - 1) * B_ + m0 + n) * H_ + kg * 8);
            #pragma unroll
            for (int kk = 8; kk < 40; ++kk) {
                bf16x8 a = ah[(kk - 8) * 4];
                ac[kk & 3] = __builtin_amdgcn_mfma_f32_16x16x32_bf16(a, wf[kk], ac[kk & 3], 0, 0, 0);
            }
        }

        f32x4 g4 = (ac[0] + ac[1]) + (ac[2] + ac[3]);

        // Elementwise with activation sharing: each quad lane activates only
        // its OWN gate (1 transcendental), then shuffles activated values.
        #pragma unroll
        for (int r = 0; r < 4; ++r) {
            float v   = g4[r] + bias;
            float act = (gq == 2) ? tanh_f(v) : sigmoid_f(v);
            float a1 = __shfl_xor(act, 1);
            float a2 = __shfl_xor(act, 2);
            float a3 = __shfl_xor(act, 3);
            float ia = (gq == 0) ? act : (gq == 1) ? a1 : (gq == 2) ? a2 : a3;
            float fa = (gq == 0) ? a1 : (gq == 1) ? act : (gq == 2) ? a3 : a2;
            float ga = (gq == 0) ? a2 : (gq == 1) ? a3 : (gq == 2) ? act : a1;
            float oa = (gq == 0) ? a3 : (gq == 1) ? a2 : (gq == 2) ? a1 : act;
            float cn = fa * cc[r] + ia * ga;
            cc[r] = cn;
            float hv = oa * tanh_f(cn);
            if (gq == 0) st[w][kg * 4 + r][n >> 2] = f2bf(hv);
        }

        // Wave-internal LDS flush, then 16 packed 8B write-through stores.
        asm volatile("s_waitcnt lgkmcnt(0)" ::: "memory");
        if (lane < 16) {
            unsigned long long pv = *(const unsigned long long*)&st[w][lane][0];
            __hip_atomic_store((unsigned long long*)(hs + ((size_t)t * B_ + m0 + lane) * H_ + blk * 4),
                               pv, __ATOMIC_RELAXED, __HIP_MEMORY_SCOPE_AGENT);
        }
        // Drain this wave's h stores to the coherence point, then post the
        // wave's arrival byte (ordered after the drained data).
        asm volatile("s_waitcnt vmcnt(0)" ::: "memory");
        if (lane == 0 && t < T_ - 1)
            __hip_atomic_store(arrB + (size_t)t * 1024 + blk * 4 + w, (unsigned char)1,
                               __ATOMIC_RELAXED, __HIP_MEMORY_SCOPE_AGENT);
    }
}

// outputs[b,t,o] = hs[t,b,:] @ W_out[o,:] + b_out[o]
__global__ __launch_bounds__(256) void out_proj(
    const unsigned short* __restrict__ hs, const unsigned short* __restrict__ Wo,
    const float* __restrict__ bout, float* __restrict__ out)
{
    const int tid = threadIdx.x, wid = tid >> 6, lane = tid & 63;
    const int n = lane & 15, kg = lane >> 4;
    const int mb = blockIdx.x >> 2, nb = blockIdx.x & 3;
    const int m0 = mb * 64 + wid * 16;
    const int n0 = nb * 64;
    f32x4 acc[4];
    f32x4 z = {0.f, 0.f, 0.f, 0.f};
    acc[0] = z; acc[1] = z; acc[2] = z; acc[3] = z;
    const bf16x8* ap = (const bf16x8*)(hs + ((size_t)(m0 + n)) * H_ + kg * 8);
    #pragma unroll 2
    for (int kk = 0; kk < 32; ++kk) {
        bf16x8 a = ap[kk * 4];
        #pragma unroll
        for (int nt = 0; nt < 4; ++nt) {
            const bf16x8* bp8 = (const bf16x8*)(Wo + ((size_t)(n0 + nt * 16 + n)) * H_ + kg * 8);
            bf16x8 b = bp8[kk * 4];
            acc[nt] = __builtin_amdgcn_mfma_f32_16x16x32_bf16(a, b, acc[nt], 0, 0, 0);
        }
    }
    #pragma unroll
    for (int nt = 0; nt < 4; ++nt) {
        int col = n0 + nt * 16 + n;
        float bias = bout[col];
        #pragma unroll
        for (int r = 0; r < 4; ++r) {
            int m = m0 + kg * 4 + r;
            int tt = m >> 6, bb = m & 63;
            out[((size_t)bb * T_ + tt) * O_ + col] = acc[nt][r] + bias;
        }
    }
}

extern "C" void kernel_launch(void* const* d_in, const int* in_sizes, int n_in,
                              void* d_out, int out_size, void* d_ws, size_t ws_size,
                              hipStream_t stream)
{
    const float* x    = (const float*)d_in[0];
    const float* Wih  = (const float*)d_in[1];
    const float* Whh  = (const float*)d_in[2];
    const float* bih  = (const float*)d_in[3];
    const float* bhh  = (const float*)d_in[4];
    const float* Wout = (const float*)d_in[5];
    const float* bout = (const float*)d_in[6];
    float* out = (float*)d_out;

    char* ws = (char*)d_ws;
    unsigned short* Wp  = (unsigned short*)ws;  ws += (size_t)4096 * KTOT * 2;   // 10485760
    float*          bpk = (float*)ws;           ws += (size_t)4096 * 4;          // 16384
    unsigned short* Wo  = (unsigned short*)ws;  ws += (size_t)O_ * H_ * 2;       // 524288
    unsigned short* xt  = (unsigned short*)ws;  ws += (size_t)T_ * B_ * D_ * 2;  // 16777216
    unsigned short* hs  = (unsigned short*)ws;  ws += (size_t)T_ * B_ * H_ * 2;  // 67108864
    int*            syn = (int*)ws;             ws += (size_t)SYNC_INTS * 4;     // 524288

    if (ws_size < (size_t)(ws - (char*)d_ws)) return;  // ~96 MB required

    zero_sync<<<SYNC_INTS / 256, 256, 0, stream>>>(syn);
    pack_weights<<<4096 + 256, 256, 0, stream>>>(Wih, Whh, bih, bhh, Wout, Wp, bpk, Wo);
    x_pack<<<B_ * T_, 256, 0, stream>>>(x, xt);

    {
        const unsigned short* Wpc = Wp;
        const float*          bpc = bpk;
        const unsigned short* xtc = xt;
        unsigned short*       hsv = hs;
        int*                  syv = syn;
        void* args[5] = {(void*)&Wpc, (void*)&bpc, (void*)&xtc, (void*)&hsv, (void*)&syv};
        hipLaunchCooperativeKernel((void*)lstm_scan, dim3(NBLK), dim3(NTHR), args, 0, stream);
    }

    out_proj<<<(T_ * B_ / 64) * 4, 256, 0, stream>>>(hs, Wo, bout, out);
}

// Round 7
// 4647.332 us; speedup vs baseline: 1.1074x; 1.1074x over previous
//
#include <hip/hip_runtime.h>

#define B_ 64
#define T_ 512
#define D_ 256
#define H_ 1024
#define O_ 256
#define KTOT 1280   // D_ + H_
#define NBLK 256
#define NTHR 256

typedef __bf16 bf16x8 __attribute__((ext_vector_type(8)));
typedef float f32x4 __attribute__((ext_vector_type(4)));

__device__ __forceinline__ unsigned short f2bf(float f) {
    unsigned int u = __builtin_bit_cast(unsigned int, f);
    unsigned int r = (u + 0x7fffu + ((u >> 16) & 1u)) >> 16;
    return (unsigned short)r;
}
__device__ __forceinline__ float sigmoid_f(float x) { return 1.f / (1.f + __expf(-x)); }
__device__ __forceinline__ float tanh_f(float x)    { return 1.f - 2.f / (1.f + __expf(2.f * x)); }

// sync: arrival bytes arr[(t*4+g)*256 + j*4 + w] — 256 B (4 lines) per (t,group).
#define SYNC_INTS (T_ * 4 * 256 / 4)   // 131072 ints = 512 KB

__global__ void zero_sync(int* s) { s[blockIdx.x * 256 + threadIdx.x] = 0; }

// Pack [W_ih | W_hh] rows into gate-interleaved bf16 rows p = 4*hcol + g
// (orig row = g*1024 + hcol); also combined bias, and W_out -> bf16.
__global__ __launch_bounds__(256) void pack_weights(
    const float* __restrict__ Wih, const float* __restrict__ Whh,
    const float* __restrict__ bih, const float* __restrict__ bhh,
    const float* __restrict__ Wout,
    unsigned short* __restrict__ Wp, float* __restrict__ bpk,
    unsigned short* __restrict__ Wo)
{
    int bid = blockIdx.x, tid = threadIdx.x;
    if (bid < 4096) {
        int g = bid & 3, hc = bid >> 2;
        int row = g * 1024 + hc;
        for (int e = tid; e < KTOT; e += 256) {
            float v = (e < D_) ? Wih[(size_t)row * D_ + e] : Whh[(size_t)row * H_ + (e - D_)];
            Wp[(size_t)bid * KTOT + e] = f2bf(v);
        }
        if (tid == 0) bpk[bid] = bih[row] + bhh[row];
    } else {
        int r = bid - 4096;
        for (int e = tid; e < H_; e += 256)
            Wo[(size_t)r * H_ + e] = f2bf(Wout[(size_t)r * H_ + e]);
    }
}

// x [B,T,D] f32 -> xt [T,B,D] bf16
__global__ __launch_bounds__(256) void x_pack(const float* __restrict__ x,
                                              unsigned short* __restrict__ xt)
{
    int bid = blockIdx.x;            // = b*512 + t
    int b = bid >> 9, t = bid & 511;
    int d = threadIdx.x;
    xt[((size_t)t * B_ + b) * D_ + d] = f2bf(x[(size_t)bid * D_ + d]);
}

// Batch-partitioned scan: group g = blk&3 owns batch rows g*16..g*16+15 for all
// 512 steps; its 64 blocks cover all 4096 packed gate columns (16/wave).
// Sync is per-group only: 256 arrival bytes (4 lines), polled by wave 0 with a
// single coalesced dword-per-lane load. No cross-group coupling.
__global__ __launch_bounds__(NTHR, 1) void lstm_scan(
    const unsigned short* __restrict__ Wp, const float* __restrict__ bpk,
    const unsigned short* __restrict__ xt, unsigned short* __restrict__ hs,
    int* __restrict__ sync)
{
    const int tid  = threadIdx.x;
    const int w    = tid >> 6, lane = tid & 63;
    const int blk  = blockIdx.x;
    const int g    = blk & 3;    // batch group
    const int j    = blk >> 2;   // column block within group
    const int n    = lane & 15, kg = lane >> 4;
    const int gq   = n & 3;
    const int pc   = j * 64 + w * 16 + n;          // packed gate column
    const int hcol = j * 16 + w * 4 + (n >> 2);    // h column (gq==0 lanes)
    const int rowb = g * 16;                       // batch row base

    unsigned char* arrB = (unsigned char*)sync;

    // Preload this wave's weight fragments: 40 x bf16x8, reused 512 steps.
    bf16x8 wf[40];
    {
        const bf16x8* wp8 = (const bf16x8*)(Wp + (size_t)pc * KTOT + kg * 8);
        #pragma unroll
        for (int kk = 0; kk < 40; ++kk) wf[kk] = wp8[kk * 4];
    }
    // Pin in registers (opaque redefinition: no remat/sinking into the loop).
    #pragma unroll
    for (int kk = 0; kk < 40; ++kk) asm volatile("" : "+v"(wf[kk]));

    const float bias = bpk[pc];

    float cc[4] = {0.f, 0.f, 0.f, 0.f};

    for (int t = 0; t < T_; ++t) {
        f32x4 ac[4];
        f32x4 z = {0.f, 0.f, 0.f, 0.f};
        ac[0] = z; ac[1] = z; ac[2] = z; ac[3] = z;

        // x-part: independent of h_{t-1}; overlaps the arrival wait below.
        {
            const bf16x8* ax = (const bf16x8*)(xt + ((size_t)t * B_ + rowb + n) * D_ + kg * 8);
            #pragma unroll
            for (int kk = 0; kk < 8; ++kk) {
                bf16x8 a = ax[kk * 4];
                ac[kk & 3] = __builtin_amdgcn_mfma_f32_16x16x32_bf16(a, wf[kk], ac[kk & 3], 0, 0, 0);
            }
        }

        if (t > 0) {
            // Wave 0 polls the group's 256 arrival bytes: one dword per lane
            // (64 lanes x 4 B = 256 B = 4 lines) -> single coalesced load per
            // poll iteration. Then one intra-block barrier releases all waves.
            if (w == 0) {
                const int* ap = (const int*)(arrB + ((size_t)(t - 1) * 4 + g) * 256) + lane;
                for (;;) {
                    int v = __hip_atomic_load(ap, __ATOMIC_RELAXED, __HIP_MEMORY_SCOPE_AGENT);
                    if (__all(v == 0x01010101)) break;
                }
            }
            __syncthreads();

            const bf16x8* ah = (const bf16x8*)(hs + ((size_t)(t - 1) * B_ + rowb + n) * H_ + kg * 8);
            #pragma unroll
            for (int kk = 8; kk < 40; ++kk) {
                bf16x8 a = ah[(kk - 8) * 4];
                ac[kk & 3] = __builtin_amdgcn_mfma_f32_16x16x32_bf16(a, wf[kk], ac[kk & 3], 0, 0, 0);
            }
        }

        f32x4 g4 = (ac[0] + ac[1]) + (ac[2] + ac[3]);

        // Elementwise with activation sharing: each quad lane activates only
        // its OWN gate (1 transcendental), then shuffles activated values.
        float hv[4];
        #pragma unroll
        for (int r = 0; r < 4; ++r) {
            float v   = g4[r] + bias;
            float act = (gq == 2) ? tanh_f(v) : sigmoid_f(v);
            float a1 = __shfl_xor(act, 1);
            float a2 = __shfl_xor(act, 2);
            float a3 = __shfl_xor(act, 3);
            float ia = (gq == 0) ? act : (gq == 1) ? a1 : (gq == 2) ? a2 : a3;
            float fa = (gq == 0) ? a1 : (gq == 1) ? act : (gq == 2) ? a3 : a2;
            float ga = (gq == 0) ? a2 : (gq == 1) ? a3 : (gq == 2) ? act : a1;
            float oa = (gq == 0) ? a3 : (gq == 1) ? a2 : (gq == 2) ? a1 : act;
            float cn = fa * cc[r] + ia * ga;
            cc[r] = cn;
            hv[r] = oa * tanh_f(cn);
        }

        // Store this wave's h slice (write-through to coherence point):
        // rows rowb + kg*4 + r, column hcol (gq==0 lanes).
        if (gq == 0) {
            #pragma unroll
            for (int r = 0; r < 4; ++r)
                __hip_atomic_store(hs + ((size_t)t * B_ + rowb + kg * 4 + r) * H_ + hcol,
                                   f2bf(hv[r]), __ATOMIC_RELAXED, __HIP_MEMORY_SCOPE_AGENT);
        }
        // Per-wave drain, then per-wave arrival byte (no block barrier needed).
        asm volatile("s_waitcnt vmcnt(0)" ::: "memory");
        if (lane == 0 && t < T_ - 1)
            __hip_atomic_store(arrB + ((size_t)t * 4 + g) * 256 + j * 4 + w, (unsigned char)1,
                               __ATOMIC_RELAXED, __HIP_MEMORY_SCOPE_AGENT);
    }
}

// outputs[b,t,o] = hs[t,b,:] @ W_out[o,:] + b_out[o]
__global__ __launch_bounds__(256) void out_proj(
    const unsigned short* __restrict__ hs, const unsigned short* __restrict__ Wo,
    const float* __restrict__ bout, float* __restrict__ out)
{
    const int tid = threadIdx.x, wid = tid >> 6, lane = tid & 63;
    const int n = lane & 15, kg = lane >> 4;
    const int mb = blockIdx.x >> 2, nb = blockIdx.x & 3;
    const int m0 = mb * 64 + wid * 16;
    const int n0 = nb * 64;
    f32x4 acc[4];
    f32x4 z = {0.f, 0.f, 0.f, 0.f};
    acc[0] = z; acc[1] = z; acc[2] = z; acc[3] = z;
    const bf16x8* ap = (const bf16x8*)(hs + ((size_t)(m0 + n)) * H_ + kg * 8);
    #pragma unroll 2
    for (int kk = 0; kk < 32; ++kk) {
        bf16x8 a = ap[kk * 4];
        #pragma unroll
        for (int nt = 0; nt < 4; ++nt) {
            const bf16x8* bp8 = (const bf16x8*)(Wo + ((size_t)(n0 + nt * 16 + n)) * H_ + kg * 8);
            bf16x8 b = bp8[kk * 4];
            acc[nt] = __builtin_amdgcn_mfma_f32_16x16x32_bf16(a, b, acc[nt], 0, 0, 0);
        }
    }
    #pragma unroll
    for (int nt = 0; nt < 4; ++nt) {
        int col = n0 + nt * 16 + n;
        float bias = bout[col];
        #pragma unroll
        for (int r = 0; r < 4; ++r) {
            int m = m0 + kg * 4 + r;
            int tt = m >> 6, bb = m & 63;
            out[((size_t)bb * T_ + tt) * O_ + col] = acc[nt][r] + bias;
        }
    }
}

extern "C" void kernel_launch(void* const* d_in, const int* in_sizes, int n_in,
                              void* d_out, int out_size, void* d_ws, size_t ws_size,
                              hipStream_t stream)
{
    const float* x    = (const float*)d_in[0];
    const float* Wih  = (const float*)d_in[1];
    const float* Whh  = (const float*)d_in[2];
    const float* bih  = (const float*)d_in[3];
    const float* bhh  = (const float*)d_in[4];
    const float* Wout = (const float*)d_in[5];
    const float* bout = (const float*)d_in[6];
    float* out = (float*)d_out;

    char* ws = (char*)d_ws;
    unsigned short* Wp  = (unsigned short*)ws;  ws += (size_t)4096 * KTOT * 2;   // 10485760
    float*          bpk = (float*)ws;           ws += (size_t)4096 * 4;          // 16384
    unsigned short* Wo  = (unsigned short*)ws;  ws += (size_t)O_ * H_ * 2;       // 524288
    unsigned short* xt  = (unsigned short*)ws;  ws += (size_t)T_ * B_ * D_ * 2;  // 16777216
    unsigned short* hs  = (unsigned short*)ws;  ws += (size_t)T_ * B_ * H_ * 2;  // 67108864
    int*            syn = (int*)ws;             ws += (size_t)SYNC_INTS * 4;     // 524288

    if (ws_size < (size_t)(ws - (char*)d_ws)) return;  // ~96 MB required

    zero_sync<<<SYNC_INTS / 256, 256, 0, stream>>>(syn);
    pack_weights<<<4096 + 256, 256, 0, stream>>>(Wih, Whh, bih, bhh, Wout, Wp, bpk, Wo);
    x_pack<<<B_ * T_, 256, 0, stream>>>(x, xt);

    {
        const unsigned short* Wpc = Wp;
        const float*          bpc = bpk;
        const unsigned short* xtc = xt;
        unsigned short*       hsv = hs;
        int*                  syv = syn;
        void* args[5] = {(void*)&Wpc, (void*)&bpc, (void*)&xtc, (void*)&hsv, (void*)&syv};
        hipLaunchCooperativeKernel((void*)lstm_scan, dim3(NBLK), dim3(NTHR), args, 0, stream);
    }

    out_proj<<<(T_ * B_ / 64) * 4, 256, 0, stream>>>(hs, Wo, bout, out);
}